// Round 1
// 525.389 us; speedup vs baseline: 1.0233x; 1.0233x over previous
//
#include <hip/hip_runtime.h>
#include <hip/hip_bf16.h>
#include <cstdint>
#include <cstddef>

#define H 256
#define CHUNK 128     // max items per pooling chunk

typedef __attribute__((ext_vector_type(8))) short    frag8;   // 8 bf16 (4 VGPRs)
typedef __attribute__((ext_vector_type(4))) float    f32x4;
typedef __attribute__((ext_vector_type(4))) uint32_t u32x4;
typedef __attribute__((ext_vector_type(8))) unsigned short ushort8;

__device__ __forceinline__ unsigned short f32_to_bf16(float f) {
    uint32_t u = __float_as_uint(f);
    u = (u + 0x7FFFu + ((u >> 16) & 1u)) >> 16;   // RNE
    return (unsigned short)u;
}

// packed f32x2 -> bf16x2 (v_cvt_pk_bf16_f32 on gfx950), a in low 16 bits
__device__ __forceinline__ uint32_t pk_bf16(float a, float b) {
    union { __hip_bfloat162 h2; uint32_t u; } cv;
    cv.h2 = __float22bfloat162_rn(make_float2(a, b));
    return cv.u;
}

// ---------------- kernel 1: prep — Wopt fragment-shuffle + Wout transpose ----------------
// Wopt layout: [ksg(16)][ct(16)][lane(64)][8 bf16] — per K-step a wave's B-frag
// loads are one contiguous stream. value = Wcat[col=ct*16+(lane&15)]
// [k = ksg*32+(lane>>4)*8+j], Wcat = concat(Wu,Wv) along k.
__global__ void prep(const float* __restrict__ Wu, const float* __restrict__ Wv,
                     const float* __restrict__ Wout,
                     unsigned short* __restrict__ Wopt, float* __restrict__ WoutT) {
    int bid = blockIdx.x, tid = threadIdx.x;
    if (bid < 64) {
        int idx  = bid * 256 + tid;        // 0..16383
        int lane = idx & 63;
        int ct   = (idx >> 6) & 15;
        int ksg  = idx >> 10;
        int col  = ct * 16 + (lane & 15);
        int kg   = ksg * 32 + (lane >> 4) * 8;
        ushort8 pk;
        #pragma unroll
        for (int j = 0; j < 8; j++) {
            int k = kg + j;
            float v = (k < 256) ? Wu[col * 256 + k] : Wv[col * 256 + (k - 256)];
            pk[j] = f32_to_bf16(v);
        }
        *(ushort8*)&Wopt[(size_t)idx * 8] = pk;
    } else {
        int t2 = (bid - 64) * 256 + tid;   // 0..65535
        int j = t2 & 255, k = t2 >> 8;
        WoutT[t2] = Wout[j * 256 + k];     // WoutT[k][j] = Wout[j][k]
    }
}

// ---------------- kernel 2: dual exclusive scan: item offsets + chunk work-list ----------------
__global__ void seg_offsets(const int* __restrict__ lens, int B, int* __restrict__ off,
                            int2* __restrict__ chunks, int* __restrict__ chunk_cnt) {
    __shared__ int partL[256], partC[256];
    int tid = threadIdx.x;
    bool is64 = (B >= 3) && (lens[1] == 0) && (lens[3] == 0) && (lens[5] == 0);
    int per = (B + 255) / 256;
    int base = tid * per;
    int sL = 0, sC = 0;
    for (int i = 0; i < per; i++) {
        int idx = base + i;
        if (idx < B) {
            int l = is64 ? lens[2 * idx] : lens[idx];
            sL += l;
            sC += (l + CHUNK - 1) / CHUNK;
        }
    }
    partL[tid] = sL; partC[tid] = sC;
    __syncthreads();
    for (int d = 1; d < 256; d <<= 1) {
        int vL = partL[tid], vC = partC[tid];
        int aL = (tid >= d) ? partL[tid - d] : 0;
        int aC = (tid >= d) ? partC[tid - d] : 0;
        __syncthreads();
        partL[tid] = vL + aL; partC[tid] = vC + aC;
        __syncthreads();
    }
    int runL = partL[tid] - sL;
    int runC = partC[tid] - sC;
    for (int i = 0; i < per; i++) {
        int idx = base + i;
        if (idx < B) {
            int l = is64 ? lens[2 * idx] : lens[idx];
            off[idx] = runL;
            int n = (l + CHUNK - 1) / CHUNK;
            for (int c = 0; c < n; c++)
                chunks[runC + c] = make_int2(idx, runL + c * CHUNK);
            runC += n;
            runL += l;
        }
    }
    if (tid == 255) { off[B] = partL[255]; chunk_cnt[0] = partC[255]; }
}

// ---------------- kernel 3: fused e = We . sigmoid(Wu f + bu + Wv c) ----------------
// 512 thr (8 waves). 64 rows x 256 cols, K=512 in 4 steps of KT=128.
// Each wave: 64 rows x 32 cols -> acc[4][2] (32 AGPR). Per kt: preload ALL 8
// B-frags (bfr[4][2]) BEFORE issuing the A-prefetch so every in-loop vmcnt wait
// is counted (targets loads older than the prefetch) and the prefetch stays in
// flight across the whole ks loop. Target <=128 regs/wave -> 4 waves/SIMD.
// LDS: 64x128 bf16 XOR-swizzled in 16B groups (group' = group ^ (row&15)).
__global__ __launch_bounds__(512, 4) void fused_e(
        const float* __restrict__ feats, const float* __restrict__ ctx,
        const unsigned short* __restrict__ Wopt,
        const float* __restrict__ bu, const float* __restrict__ We,
        float* __restrict__ e_out) {
    __shared__ unsigned short a_lds[64 * 128];   // 16 KB
    __shared__ float e_part[8 * 64];             // 2 KB

    const int tid  = threadIdx.x;
    const int lane = tid & 63;
    const int w    = tid >> 6;          // wave 0..7 -> cols w*32..w*32+31
    const int l15  = lane & 15;
    const int q    = lane >> 4;
    const size_t m0 = (size_t)blockIdx.x * 64;
    const int r0   = tid >> 3;          // staging row 0..63
    const int c8   = tid & 7;           // 16-float chunk within 128 cols
    const int swz  = r0 & 15;

    f32x4 acc[4][2];
    #pragma unroll
    for (int i = 0; i < 4; i++)
        #pragma unroll
        for (int j = 0; j < 2; j++)
            acc[i][j] = (f32x4)(0.0f);

    f32x4 pre[4];
    {
        const float* p = feats + (m0 + r0) * H + c8 * 16;
        pre[0] = *(const f32x4*)p;       pre[1] = *(const f32x4*)(p + 4);
        pre[2] = *(const f32x4*)(p + 8); pre[3] = *(const f32x4*)(p + 12);
    }

    #pragma unroll
    for (int kt = 0; kt < 4; ++kt) {
        u32x4 g0, g1;
        g0[0] = pk_bf16(pre[0][0], pre[0][1]); g0[1] = pk_bf16(pre[0][2], pre[0][3]);
        g0[2] = pk_bf16(pre[1][0], pre[1][1]); g0[3] = pk_bf16(pre[1][2], pre[1][3]);
        g1[0] = pk_bf16(pre[2][0], pre[2][1]); g1[1] = pk_bf16(pre[2][2], pre[2][3]);
        g1[2] = pk_bf16(pre[3][0], pre[3][1]); g1[3] = pk_bf16(pre[3][2], pre[3][3]);

        __syncthreads();                 // prior kt's fragment reads done
        *(u32x4*)&a_lds[r0 * 128 + (((2 * c8    ) ^ swz) * 8)] = g0;
        *(u32x4*)&a_lds[r0 * 128 + (((2 * c8 + 1) ^ swz) * 8)] = g1;
        __syncthreads();                 // writes visible

        // B preload: all 4 ks x 2 ci for this kt (8 frag8 = 32 VGPR).
        // Issued BEFORE the A-prefetch so waits on them never drain it.
        frag8 bfr[4][2];
        #pragma unroll
        for (int ks = 0; ks < 4; ++ks)
            #pragma unroll
            for (int ci = 0; ci < 2; ++ci)
                bfr[ks][ci] = *(const frag8*)&Wopt[
                    (((size_t)(kt * 4 + ks) * 16 + (w * 2 + ci)) * 64 + lane) * 8];
        __builtin_amdgcn_sched_barrier(0);   // pin: B issues before A-prefetch

        if (kt < 3) {                    // A-prefetch; stays in flight over ks loop
            const float* src = (kt + 1 < 2) ? feats : ctx;
            const int kb = ((kt + 1) & 1) * 128;
            const float* p = src + (m0 + r0) * H + kb + c8 * 16;
            pre[0] = *(const f32x4*)p;       pre[1] = *(const f32x4*)(p + 4);
            pre[2] = *(const f32x4*)(p + 8); pre[3] = *(const f32x4*)(p + 12);
        }

        #pragma unroll
        for (int ks = 0; ks < 4; ++ks) {
            frag8 afr[4];
            #pragma unroll
            for (int rt = 0; rt < 4; ++rt)
                afr[rt] = *(const frag8*)&a_lds[(rt * 16 + l15) * 128 + (((ks * 4 + q) ^ l15) * 8)];
            #pragma unroll
            for (int rt = 0; rt < 4; ++rt)
                #pragma unroll
                for (int ci = 0; ci < 2; ++ci)
                    acc[rt][ci] = __builtin_amdgcn_mfma_f32_16x16x32_bf16(
                        afr[rt], bfr[ks][ci], acc[rt][ci], 0, 0, 0);
        }
    }

    // epilogue: e_row = sum_col We[col] * sigmoid(h + bu[col]); wave covers 32 cols
    float buv[2], wev[2];
    #pragma unroll
    for (int ci = 0; ci < 2; ++ci) {
        int col = w * 32 + ci * 16 + l15;
        buv[ci] = bu[col];
        wev[ci] = We[col];
    }
    #pragma unroll
    for (int rt = 0; rt < 4; ++rt) {
        #pragma unroll
        for (int r = 0; r < 4; ++r) {
            float s = 0.0f;
            #pragma unroll
            for (int ci = 0; ci < 2; ++ci) {
                float h = acc[rt][ci][r] + buv[ci];
                s += wev[ci] * __builtin_amdgcn_rcpf(1.0f + __expf(-h));
            }
            s += __shfl_xor(s, 1, 64);
            s += __shfl_xor(s, 2, 64);
            s += __shfl_xor(s, 4, 64);
            s += __shfl_xor(s, 8, 64);
            if (l15 == 0) e_part[w * 64 + rt * 16 + q * 4 + r] = s;
        }
    }
    __syncthreads();
    if (tid < 64) {
        float s = 0.0f;
        #pragma unroll
        for (int ww = 0; ww < 8; ++ww) s += e_part[ww * 64 + tid];
        e_out[m0 + tid] = s;
    }
}

// ---------------- kernel 4: per-segment softmax stats; alpha written IN PLACE over e ----------------
__global__ __launch_bounds__(256) void seg_stats(
        float* __restrict__ e, const int* __restrict__ off, int B) {
    int seg = blockIdx.x * 4 + (threadIdx.x >> 6);
    int lane = threadIdx.x & 63;
    if (seg >= B) return;
    int start = off[seg];
    int len = off[seg + 1] - start;
    float m = -3.0e38f;
    for (int i = lane; i < len; i += 64) m = fmaxf(m, e[start + i]);
    #pragma unroll
    for (int o = 32; o > 0; o >>= 1) m = fmaxf(m, __shfl_xor(m, o, 64));
    float s = 0.0f;
    for (int i = lane; i < len; i += 64) s += __expf(e[start + i] - m);
    #pragma unroll
    for (int o = 32; o > 0; o >>= 1) s += __shfl_xor(s, o, 64);
    float inv = (s > 0.0f) ? 1.0f / s : 0.0f;
    for (int i = lane; i < len; i += 64) e[start + i] = __expf(e[start + i] - m) * inv;
}

// ---------------- kernel 5: chunked weighted pooling (alpha-stream, dual chains) ----------------
__global__ __launch_bounds__(256) void pool_chunks(
        const float* __restrict__ alpha, const float* __restrict__ feats,
        const int* __restrict__ off, const int2* __restrict__ chunks,
        const int* __restrict__ chunk_cnt, float* __restrict__ rst) {
    __shared__ float redf[4 * 256];
    int idx = blockIdx.x;
    if (idx >= chunk_cnt[0]) return;
    int2 en = chunks[idx];
    int seg = en.x, cstart = en.y;
    int sstart = off[seg], send = off[seg + 1];
    int clen = send - cstart;
    if (clen > CHUNK) clen = CHUNK;
    int tid = threadIdx.x, lane = tid & 63, g = tid >> 6;

    const f32x4* F = (const f32x4*)feats + (size_t)cstart * 64 + lane;
    const float* A = alpha + cstart;
    f32x4 acc0 = (f32x4)(0.0f), acc1 = (f32x4)(0.0f);
    int i = g;
    for (; i + 4 < clen; i += 8) {
        acc0 += A[i]     * F[(size_t)i * 64];
        acc1 += A[i + 4] * F[(size_t)(i + 4) * 64];
    }
    if (i < clen) acc0 += A[i] * F[(size_t)i * 64];
    acc0 += acc1;
    *(f32x4*)&redf[g * 256 + lane * 4] = acc0;
    __syncthreads();
    float v = redf[tid] + redf[256 + tid] + redf[512 + tid] + redf[768 + tid];
    if (send - sstart > CHUNK) atomicAdd(&rst[(size_t)seg * H + tid], v);
    else rst[(size_t)seg * H + tid] = v;
}

// ---------------- kernel 6: out = rst @ Wout.T (via WoutT) ----------------
#define RB 8
__global__ __launch_bounds__(256) void out_gemm(
        const float* __restrict__ rst, const float* __restrict__ WoutT,
        float* __restrict__ out) {
    __shared__ float r[RB * 256];
    const int tid = threadIdx.x;
    const size_t b0 = (size_t)blockIdx.x * RB;
    for (int i = tid; i < RB * 256; i += 256) r[i] = rst[b0 * 256 + i];
    __syncthreads();
    float acc[RB];
    #pragma unroll
    for (int j = 0; j < RB; j++) acc[j] = 0.0f;
    for (int k = 0; k < 256; k += 4) {
        f32x4 rw[RB];
        #pragma unroll
        for (int j = 0; j < RB; j++) rw[j] = *(const f32x4*)&r[j * 256 + k];
        #pragma unroll
        for (int kk = 0; kk < 4; kk++) {
            float wv = WoutT[(size_t)(k + kk) * 256 + tid];
            #pragma unroll
            for (int j = 0; j < RB; j++) acc[j] += rw[j][kk] * wv;
        }
    }
    #pragma unroll
    for (int j = 0; j < RB; j++) out[(b0 + j) * 256 + tid] = acc[j];
}

// ---------------- launch ----------------
extern "C" void kernel_launch(void* const* d_in, const int* in_sizes, int n_in,
                              void* d_out, int out_size, void* d_ws, size_t ws_size,
                              hipStream_t stream) {
    const float* feats = (const float*)d_in[0];
    const float* ctx   = (const float*)d_in[1];
    const int*   lens  = (const int*)d_in[2];
    const float* Wu    = (const float*)d_in[3];
    const float* bu    = (const float*)d_in[4];
    const float* Wv    = (const float*)d_in[5];
    const float* We    = (const float*)d_in[6];
    const float* Wout  = (const float*)d_in[7];
    float* out = (float*)d_out;

    const int N = in_sizes[0] / H;    // 204800
    const int B = in_sizes[2];        // 4096
    const int maxChunks = B + (N + CHUNK - 1) / CHUNK;

    char* w = (char*)d_ws;
    auto carve = [&](size_t bytes) {
        char* p = w;
        w += (bytes + 255) & ~(size_t)255;
        return p;
    };
    int*            off    = (int*)           carve((size_t)(B + 1) * sizeof(int));
    float*          e      = (float*)         carve((size_t)N * sizeof(float));
    float*          rst    = (float*)         carve((size_t)B * H * sizeof(float));
    unsigned short* Wopt   = (unsigned short*)carve((size_t)16 * 16 * 64 * 8 * sizeof(unsigned short));
    float*          WoutT  = (float*)         carve((size_t)H * H * sizeof(float));
    int2*           chunks = (int2*)          carve((size_t)maxChunks * sizeof(int2));
    int*            ccnt   = (int*)           carve(sizeof(int));

    hipMemsetAsync(rst, 0, (size_t)B * H * sizeof(float), stream);  // for atomic combine

    prep        <<<320,         256, 0, stream>>>(Wu, Wv, Wout, Wopt, WoutT);
    seg_offsets <<<1,           256, 0, stream>>>(lens, B, off, chunks, ccnt);
    fused_e     <<<N / 64,      512, 0, stream>>>(feats, ctx, Wopt, bu, We, e);
    seg_stats   <<<(B + 3) / 4, 256, 0, stream>>>(e, off, B);
    pool_chunks <<<maxChunks,   256, 0, stream>>>(e, feats, off, chunks, ccnt, rst);
    out_gemm    <<<B / RB,      256, 0, stream>>>(rst, WoutT, out);
}